// Round 6
// baseline (79.358 us; speedup 1.0000x reference)
//
#include <hip/hip_runtime.h>

// MultiLinear: out[i] = inputs[i] @ w[indices[i]] + b[indices[i]]
// B=16384, OPT=64, IN=128, OUT=128, fp32 in/out, int32 indices.
//
// v4fix: v4 with the staging-loop indexing bug fixed. v4/v4r aborted because
// the 64-col row has 16 float4 chunks (k = e>>4, c = e&15) but the code used
// k = e>>2, c = e&3 -> k ran to 511: OOB reads past w AND OOB LDS writes ->
// memory fault -> abort. Deterministic, explained.
//
// Structure (v4): grid = 64 options x 8 slices x 2 n-halves = 1024 blocks
// = 4 blocks/CU = 16 waves/CU (2x v3 occupancy). Per-block w staging is a
// 64-col half (16 KB bf16 LDS); B-frag build is 32 scalar ds_read_u16 per
// thread; one MFMA chain per wave; fused bias; coalesced stores.

#define B_TOT     16384
#define NOPT      64
#define DIN       128
#define DOUT      128
#define NSLICE    8
#define SLICE_LEN (B_TOT / NSLICE)   // 2048
#define NTHREADS  256
#define SPN       68                 // LDS row stride (u16) for 64 cols; 136 B

typedef __attribute__((ext_vector_type(8))) short  short8;
typedef __attribute__((ext_vector_type(4))) float  floatx4;

static __device__ __forceinline__ short f2bf(float f) {
    // round-to-nearest-even fp32 -> bf16 (finite normals; no NaN path)
    union { float f; unsigned u; } v; v.f = f;
    unsigned r = v.u + 0x7fffu + ((v.u >> 16) & 1u);
    return (short)(r >> 16);
}

__global__ __launch_bounds__(NTHREADS, 4)
void multilinear_kernel(const float* __restrict__ x,
                        const float* __restrict__ w,
                        const float* __restrict__ bias,
                        const int*   __restrict__ idx,
                        float* __restrict__ out) {
    __shared__ __align__(16) unsigned short s_w[DIN * SPN];  // 17408 B
    __shared__ unsigned short s_list[SLICE_LEN];             // 4096 B
    __shared__ int s_cnt;

    const int bid = blockIdx.x;
    const int o = bid & (NOPT - 1);        // option
    const int s = (bid >> 6) & (NSLICE-1); // slice 0..7
    const int h = bid >> 9;                // n-half 0/1
    const int t = threadIdx.x;

    if (t == 0) s_cnt = 0;
    __syncthreads();

    // --- stage w[o][:, h*64 .. h*64+64) fp32 -> LDS bf16, coalesced float4 ---
    // 128 rows x 16 float4-chunks/row = 2048 chunks, 8 iters x 256 threads.
    const float* wo = w + (size_t)o * (DIN * DOUT) + h * 64;
    #pragma unroll
    for (int it = 0; it < 8; ++it) {
        const int e = it * NTHREADS + t;      // chunk id, 0..2047
        const int k = e >> 4;                 // row (k) 0..127
        const int c = e & 15;                 // float4-chunk within 64-col row
        float4 v = *(const float4*)(wo + (size_t)k * DOUT + c * 4);
        ushort4 hh;
        hh.x = (unsigned short)f2bf(v.x); hh.y = (unsigned short)f2bf(v.y);
        hh.z = (unsigned short)f2bf(v.z); hh.w = (unsigned short)f2bf(v.w);
        *(ushort4*)(&s_w[k * SPN + c * 4]) = hh;   // 8 B aligned (136k + 8c)
    }

    // --- scan slice for matching rows (int4 loads, order irrelevant) ---
    const int base = s * SLICE_LEN;
    const int4* ip = (const int4*)(idx + base);
    #pragma unroll
    for (int it = 0; it < SLICE_LEN / (4 * NTHREADS); ++it) {
        const int e = it * NTHREADS + t;
        int4 v = ip[e];
        const int i0 = base + e * 4;
        if (v.x == o) s_list[atomicAdd(&s_cnt, 1)] = (unsigned short)(i0 + 0);
        if (v.y == o) s_list[atomicAdd(&s_cnt, 1)] = (unsigned short)(i0 + 1);
        if (v.z == o) s_list[atomicAdd(&s_cnt, 1)] = (unsigned short)(i0 + 2);
        if (v.w == o) s_list[atomicAdd(&s_cnt, 1)] = (unsigned short)(i0 + 3);
    }
    __syncthreads();

    const int count = s_cnt;
    if (count == 0) return;

    const int wave = t >> 6;     // 0..3 -> n-tile within half
    const int lane = t & 63;
    const int l15  = lane & 15;
    const int quad = lane >> 4;  // 0..3

    const int nloc  = wave * 16 + l15;     // 0..63 (LDS col)
    const int nglob = h * 64 + nloc;       // output col

    // --- build B fragment once per block (one-time scalar LDS reads) ---
    // B[k][n]: lane holds k = kb*32 + quad*8 + j, n = nglob
    short8 bf[4];
    #pragma unroll
    for (int kb = 0; kb < 4; ++kb)
        #pragma unroll
        for (int j = 0; j < 8; ++j)
            bf[kb][j] = (short)s_w[(kb * 32 + quad * 8 + j) * SPN + nloc];

    const float bv = bias[o * DOUT + nglob];

    // --- 16-row M-tiles over matched rows ---
    const int mtiles = (count + 15) >> 4;
    for (int mt = 0; mt < mtiles; ++mt) {
        const int am = mt * 16 + l15;
        const int arid = s_list[am < count ? am : count - 1];
        const float* xr = x + (size_t)arid * DIN;

        floatx4 acc = {0.f, 0.f, 0.f, 0.f};
        #pragma unroll
        for (int kb = 0; kb < 4; ++kb) {
            const int k0 = kb * 32 + quad * 8;       // 32B-aligned
            float4 xa = *(const float4*)(xr + k0);
            float4 xb = *(const float4*)(xr + k0 + 4);
            short8 af;
            af[0] = f2bf(xa.x); af[1] = f2bf(xa.y);
            af[2] = f2bf(xa.z); af[3] = f2bf(xa.w);
            af[4] = f2bf(xb.x); af[5] = f2bf(xb.y);
            af[6] = f2bf(xb.z); af[7] = f2bf(xb.w);
            acc = __builtin_amdgcn_mfma_f32_16x16x32_bf16(af, bf[kb], acc, 0, 0, 0);
        }

        // C/D: col = l15, row = quad*4 + r
        #pragma unroll
        for (int r = 0; r < 4; ++r) {
            const int m = mt * 16 + quad * 4 + r;
            if (m < count) {
                const int rid = s_list[m];
                out[(size_t)rid * DOUT + nglob] = acc[r] + bv;
            }
        }
    }
}

extern "C" void kernel_launch(void* const* d_in, const int* in_sizes, int n_in,
                              void* d_out, int out_size, void* d_ws, size_t ws_size,
                              hipStream_t stream) {
    const float* x    = (const float*)d_in[0];  // [16384,128]
    const float* w    = (const float*)d_in[1];  // [64,128,128]
    const float* bias = (const float*)d_in[2];  // [64,128]
    const int*   idx  = (const int*)d_in[3];    // [16384]
    float* out        = (float*)d_out;          // [16384,128]

    multilinear_kernel<<<NOPT * NSLICE * 2, NTHREADS, 0, stream>>>(x, w, bias, idx, out);
}

// Round 7
// 74.692 us; speedup vs baseline: 1.0625x; 1.0625x over previous
//
#include <hip/hip_runtime.h>

// MultiLinear: out[i] = inputs[i] @ w[indices[i]] + b[indices[i]]
// B=16384, OPT=64, IN=128, OUT=128, fp32 in/out, int32 indices.
//
// v5 = v3 verbatim (best-measured variant, 74.8 us) restored after v4's
// N-split (16 waves/CU) measured WORSE (79.4): doubled idx-scan + x-gather
// traffic outweighed latency hiding, and/or round-to-round noise (harness
// fills vary +/-10%; our kernel is ~5 us of a ~75 us total). This round
// re-establishes the best kernel and the noise floor.
//
// Structure: grid = 64 options x 8 slices = 512 blocks. Each block:
//   - stages w[o] natural-layout [k][n] fp32 -> LDS bf16 (coalesced float4
//     + inline cvt; SPN=132 padded rows), overlapped with idx scan; 1 barrier
//   - compacts matching row ids (ushort) from its 2048-idx slice
//   - builds MFMA B-fragments once per block (64 scalar ds_read_u16/thread,
//     one-time, ~2-way conflicts = free)
//   - 16-row M-tiles: A gathered from x (fp32->bf16 inline),
//     mfma_f32_16x16x32_bf16, fused bias, coalesced stores.

#define B_TOT     16384
#define NOPT      64
#define DIN       128
#define DOUT      128
#define NSLICE    8
#define SLICE_LEN (B_TOT / NSLICE)   // 2048
#define NTHREADS  256
#define SPN       132                // LDS row stride (bf16 elems); 264 B

typedef __attribute__((ext_vector_type(8))) short  short8;
typedef __attribute__((ext_vector_type(4))) float  floatx4;

static __device__ __forceinline__ short f2bf(float f) {
    // round-to-nearest-even fp32 -> bf16 (finite normals; no NaN path)
    union { float f; unsigned u; } v; v.f = f;
    unsigned r = v.u + 0x7fffu + ((v.u >> 16) & 1u);
    return (short)(r >> 16);
}

__global__ __launch_bounds__(NTHREADS, 4)
void multilinear_kernel(const float* __restrict__ x,
                        const float* __restrict__ w,
                        const float* __restrict__ bias,
                        const int*   __restrict__ idx,
                        float* __restrict__ out) {
    __shared__ __align__(16) unsigned short s_w[DIN * SPN];  // 33792 B
    __shared__ unsigned short s_list[SLICE_LEN];             // 4096 B
    __shared__ int s_cnt;

    const int o = blockIdx.x & (NOPT - 1);   // option
    const int s = blockIdx.x >> 6;           // slice 0..7
    const int t = threadIdx.x;

    if (t == 0) s_cnt = 0;
    __syncthreads();

    // --- stage w[o] (fp32, natural [k][n]) -> LDS bf16, coalesced float4 ---
    // 128 rows x 32 float4-chunks/row = 4096 chunks = 16 iters x 256 thr.
    const float* wo = w + (size_t)o * (DIN * DOUT);
    #pragma unroll
    for (int it = 0; it < 16; ++it) {
        const int e = it * NTHREADS + t;      // chunk id, 0..4095
        const int k = e >> 5;                 // row (k) 0..127
        const int c = e & 31;                 // float4-chunk within 128-col row
        float4 v = ((const float4*)wo)[e];
        ushort4 h;
        h.x = (unsigned short)f2bf(v.x); h.y = (unsigned short)f2bf(v.y);
        h.z = (unsigned short)f2bf(v.z); h.w = (unsigned short)f2bf(v.w);
        *(ushort4*)(&s_w[k * SPN + c * 4]) = h;   // 8 B, aligned (264k+8c)
    }

    // --- scan slice for matching rows (int4 loads, order irrelevant) ---
    const int base = s * SLICE_LEN;
    const int4* ip = (const int4*)(idx + base);
    #pragma unroll
    for (int it = 0; it < SLICE_LEN / (4 * NTHREADS); ++it) {
        const int e = it * NTHREADS + t;
        int4 v = ip[e];
        const int i0 = base + e * 4;
        if (v.x == o) s_list[atomicAdd(&s_cnt, 1)] = (unsigned short)(i0 + 0);
        if (v.y == o) s_list[atomicAdd(&s_cnt, 1)] = (unsigned short)(i0 + 1);
        if (v.z == o) s_list[atomicAdd(&s_cnt, 1)] = (unsigned short)(i0 + 2);
        if (v.w == o) s_list[atomicAdd(&s_cnt, 1)] = (unsigned short)(i0 + 3);
    }
    __syncthreads();

    const int count = s_cnt;
    if (count == 0) return;

    const int wave = t >> 6;     // 0..3 -> n-tiles {2w, 2w+1}
    const int lane = t & 63;
    const int l15  = lane & 15;
    const int quad = lane >> 4;  // 0..3

    const int n0 = (wave * 2) * 16 + l15;
    const int n1 = n0 + 16;

    // --- build B fragments once per block (one-time scalar LDS reads) ---
    // B[k][n]: lane holds k = kb*32 + quad*8 + j, n fixed per ntile
    short8 bf[4][2];
    #pragma unroll
    for (int kb = 0; kb < 4; ++kb) {
        #pragma unroll
        for (int j = 0; j < 8; ++j) {
            const int k = kb * 32 + quad * 8 + j;
            bf[kb][0][j] = (short)s_w[k * SPN + n0];
            bf[kb][1][j] = (short)s_w[k * SPN + n1];
        }
    }

    const float bv0 = bias[o * DOUT + n0];
    const float bv1 = bias[o * DOUT + n1];

    // --- 16-row M-tiles over matched rows ---
    const int mtiles = (count + 15) >> 4;
    for (int mt = 0; mt < mtiles; ++mt) {
        const int am = mt * 16 + l15;
        const int arid = s_list[am < count ? am : count - 1];
        const float* xr = x + (size_t)arid * DIN;

        floatx4 acc0 = {0.f, 0.f, 0.f, 0.f};
        floatx4 acc1 = {0.f, 0.f, 0.f, 0.f};
        #pragma unroll
        for (int kb = 0; kb < 4; ++kb) {
            const int k0 = kb * 32 + quad * 8;       // 32B-aligned
            float4 xa = *(const float4*)(xr + k0);
            float4 xb = *(const float4*)(xr + k0 + 4);
            short8 af;
            af[0] = f2bf(xa.x); af[1] = f2bf(xa.y);
            af[2] = f2bf(xa.z); af[3] = f2bf(xa.w);
            af[4] = f2bf(xb.x); af[5] = f2bf(xb.y);
            af[6] = f2bf(xb.z); af[7] = f2bf(xb.w);
            acc0 = __builtin_amdgcn_mfma_f32_16x16x32_bf16(af, bf[kb][0], acc0, 0, 0, 0);
            acc1 = __builtin_amdgcn_mfma_f32_16x16x32_bf16(af, bf[kb][1], acc1, 0, 0, 0);
        }

        // C/D: col = l15, row = quad*4 + r
        #pragma unroll
        for (int r = 0; r < 4; ++r) {
            const int m = mt * 16 + quad * 4 + r;
            if (m < count) {
                const int rid = s_list[m];
                out[(size_t)rid * DOUT + n0] = acc0[r] + bv0;
                out[(size_t)rid * DOUT + n1] = acc1[r] + bv1;
            }
        }
    }
}

extern "C" void kernel_launch(void* const* d_in, const int* in_sizes, int n_in,
                              void* d_out, int out_size, void* d_ws, size_t ws_size,
                              hipStream_t stream) {
    const float* x    = (const float*)d_in[0];  // [16384,128]
    const float* w    = (const float*)d_in[1];  // [64,128,128]
    const float* bias = (const float*)d_in[2];  // [64,128]
    const int*   idx  = (const int*)d_in[3];    // [16384]
    float* out        = (float*)d_out;          // [16384,128]

    multilinear_kernel<<<NOPT * NSLICE, NTHREADS, 0, stream>>>(x, w, bias, idx, out);
}